// Round 10
// baseline (480.639 us; speedup 1.0000x reference)
//
#include <hip/hip_runtime.h>
#include <stdint.h>

typedef __attribute__((ext_vector_type(8))) short short8;
typedef __attribute__((ext_vector_type(4))) short short4v;
typedef __attribute__((ext_vector_type(4))) float f32x4;

#define DEV static __device__ __forceinline__

static constexpr int LL = 2048;
static constexpr int DD = 1024;
static constexpr long long BLD = 8388608LL; // 4*2048*1024

DEV short f2bf(float f) {
    uint32_t u = __builtin_bit_cast(uint32_t, f);
    u += 0x7fffu + ((u >> 16) & 1u);   // RNE
    return (short)(u >> 16);
}
DEV float bf2f(short s) {
    uint32_t u = ((uint32_t)(uint16_t)s) << 16;
    return __builtin_bit_cast(float, u);
}

DEV float waveSum(float v) {
#pragma unroll
    for (int o = 32; o; o >>= 1) v += __shfl_down(v, o);
    return v;
}
DEV float waveMax(float v) {
#pragma unroll
    for (int o = 32; o; o >>= 1) v = fmaxf(v, __shfl_down(v, o));
    return v;
}

DEV void gload16(const void* g, void* l) {
    __builtin_amdgcn_global_load_lds(
        (const __attribute__((address_space(1))) uint32_t*)(uintptr_t)g,
        (__attribute__((address_space(3))) uint32_t*)(uintptr_t)l,
        16, 0, 0);
}

// ---------------- elementwise / reduction kernels ----------------

__global__ __launch_bounds__(256) void k_zero1(float* p) {
    if (threadIdx.x == 0) *p = 0.f;
}

__global__ __launch_bounds__(256) void k_f32_to_bf16(const float* __restrict__ in,
                                                     short* __restrict__ out, int n8) {
    int i = blockIdx.x * 256 + threadIdx.x;
    if (i >= n8) return;
    const float4* p = (const float4*)(in + (long long)i * 8);
    float4 a = p[0], b = p[1];
    short8 o;
    o[0] = f2bf(a.x); o[1] = f2bf(a.y); o[2] = f2bf(a.z); o[3] = f2bf(a.w);
    o[4] = f2bf(b.x); o[5] = f2bf(b.y); o[6] = f2bf(b.z); o[7] = f2bf(b.w);
    *(short8*)(out + (long long)i * 8) = o;
}

// convert 8 D*D fp32 weights to bf16 destinations in one launch (512 blocks each)
__global__ __launch_bounds__(256) void k_wcat(
    const float* wq, const float* wk, const float* wv,
    const float* pq, const float* pk, const float* pv,
    const float* wg, const float* wo,
    short* Wqkv, short* Pqkv, short* Wg, short* Wo) {
    const int bid = blockIdx.x;            // 4096 blocks
    const int w = bid >> 9;                // which weight
    const long long i = (long long)((bid & 511) * 256 + threadIdx.x) * 8;
    const float* src; short* dst;
    switch (w) {
        case 0: src = wq; dst = Wqkv;                break;
        case 1: src = wk; dst = Wqkv + 1048576;      break;
        case 2: src = wv; dst = Wqkv + 2097152;      break;
        case 3: src = pq; dst = Pqkv;                break;
        case 4: src = pk; dst = Pqkv + 1048576;      break;
        case 5: src = pv; dst = Pqkv + 2097152;      break;
        case 6: src = wg; dst = Wg;                  break;
        default: src = wo; dst = Wo;                 break;
    }
    const float4* p = (const float4*)(src + i);
    float4 a = p[0], b = p[1];
    short8 o;
    o[0] = f2bf(a.x); o[1] = f2bf(a.y); o[2] = f2bf(a.z); o[3] = f2bf(a.w);
    o[4] = f2bf(b.x); o[5] = f2bf(b.y); o[6] = f2bf(b.z); o[7] = f2bf(b.w);
    *(short8*)(dst + i) = o;
}

// concat 6 length-1024 fp32 bias vectors into bqkv[3072] and bpw[3072]
__global__ __launch_bounds__(256) void k_biascat(
    const float* bq, const float* bk, const float* bv,
    const float* pq, const float* pk, const float* pv,
    float* bqkv, float* bpw) {
    const int idx = blockIdx.x * 256 + threadIdx.x;  // 24 blocks -> 6144
    const int sel = idx >> 10, j = idx & 1023;
    const float* s;
    switch (sel) {
        case 0: s = bq; break; case 1: s = bk; break; case 2: s = bv; break;
        case 3: s = pq; break; case 4: s = pk; break; default: s = pv; break;
    }
    float v = s[j];
    if (sel < 3) bqkv[sel * 1024 + j] = v;
    else         bpw[(sel - 3) * 1024 + j] = v;
}

// fused depthwise conv over L (k=3, pad 1) + bias, all 3 branches.
// Each thread: one 8-channel chunk x 8 consecutive L rows (register sliding
// window); weights as 6x float4 + 2x float4 -> 26 coalesced VMEM/8 rows.
__global__ __launch_bounds__(256) void k_dwconv3b(const short* __restrict__ in,
                                                  const float* __restrict__ dwq,
                                                  const float* __restrict__ dwk,
                                                  const float* __restrict__ dwv,
                                                  const float* __restrict__ dbq,
                                                  const float* __restrict__ dbk,
                                                  const float* __restrict__ dbv,
                                                  short* __restrict__ outp) {
    const int idx = blockIdx.x * 256 + threadIdx.x;  // 3*4*256*128 = 393216
    const int d8 = idx & 127;
    const int lc = (idx >> 7) & 255;
    const int b  = (idx >> 15) & 3;
    const int br = idx >> 17;                         // uniform per block
    const float* dw = (br == 0) ? dwq : (br == 1) ? dwk : dwv;
    const float* db = (br == 0) ? dbq : (br == 1) ? dbk : dbv;

    float w[24], bb[8];
    {
        const float4* wp = (const float4*)(dw + d8 * 24);
#pragma unroll
        for (int i = 0; i < 6; i++) {
            float4 t = wp[i];
            w[i * 4 + 0] = t.x; w[i * 4 + 1] = t.y;
            w[i * 4 + 2] = t.z; w[i * 4 + 3] = t.w;
        }
        const float4* bp = (const float4*)(db + d8 * 8);
        float4 t0 = bp[0], t1 = bp[1];
        bb[0] = t0.x; bb[1] = t0.y; bb[2] = t0.z; bb[3] = t0.w;
        bb[4] = t1.x; bb[5] = t1.y; bb[6] = t1.z; bb[7] = t1.w;
    }

    const int l0 = lc * 8;
    const long long base = ((long long)(b * LL + l0)) * 3072 + br * 1024 + d8 * 8;
    short8 xr[10];
#pragma unroll
    for (int i = 0; i < 10; i++) {
        const int l = l0 - 1 + i;
        if (l >= 0 && l < LL) xr[i] = *(const short8*)(in + base + (long long)(i - 1) * 3072);
        else { short8 z = {0, 0, 0, 0, 0, 0, 0, 0}; xr[i] = z; }
    }
#pragma unroll
    for (int j = 0; j < 8; j++) {
        short8 o;
#pragma unroll
        for (int c = 0; c < 8; c++) {
            float v = bb[c] + w[c * 3 + 0] * bf2f(xr[j][c])
                            + w[c * 3 + 1] * bf2f(xr[j + 1][c])
                            + w[c * 3 + 2] * bf2f(xr[j + 2][c]);
            o[c] = f2bf(v);
        }
        *(short8*)(outp + base + (long long)j * 3072) = o;
    }
}

// in-place row L2 normalize, row = blockIdx.x, D=1024, 256 thr * 4
__global__ __launch_bounds__(256) void k_l2norm(short* __restrict__ xp) {
    __shared__ float red[4];
    const long long row = blockIdx.x;
    short* p = xp + row * DD;
    const int t = threadIdx.x;
    short4v v = *(short4v*)(p + t * 4);
    float f0 = bf2f(v[0]), f1 = bf2f(v[1]), f2 = bf2f(v[2]), f3 = bf2f(v[3]);
    float ss = f0 * f0 + f1 * f1 + f2 * f2 + f3 * f3;
    ss = waveSum(ss);
    if ((t & 63) == 0) red[t >> 6] = ss;
    __syncthreads();
    ss = (red[0] + red[1]) + (red[2] + red[3]);
    float s = 1.f / fmaxf(sqrtf(ss), 1e-12f);
    v[0] = f2bf(f0 * s); v[1] = f2bf(f1 * s); v[2] = f2bf(f2 * s); v[3] = f2bf(f3 * s);
    *(short4v*)(p + t * 4) = v;
}

// in-place row softmax, width 2048 bf16, row = blockIdx.x
__global__ __launch_bounds__(256) void k_softmax(short* __restrict__ sp) {
    __shared__ float redM[4], redS[4];
    const long long row = blockIdx.x;
    short* p = sp + row * 2048;
    const int t = threadIdx.x;
    short8 v = *(short8*)(p + t * 8);
    float f[8];
    float m = -3.0e38f;
#pragma unroll
    for (int j = 0; j < 8; j++) { f[j] = bf2f(v[j]); m = fmaxf(m, f[j]); }
    m = waveMax(m);
    if ((t & 63) == 0) redM[t >> 6] = m;
    __syncthreads();
    m = fmaxf(fmaxf(redM[0], redM[1]), fmaxf(redM[2], redM[3]));
    float s = 0.f;
#pragma unroll
    for (int j = 0; j < 8; j++) { f[j] = __expf(f[j] - m); s += f[j]; }
    s = waveSum(s);
    if ((t & 63) == 0) redS[t >> 6] = s;
    __syncthreads();
    s = (redS[0] + redS[1]) + (redS[2] + redS[3]);
    float inv = 1.f / s;
#pragma unroll
    for (int j = 0; j < 8; j++) v[j] = f2bf(f[j] * inv);
    *(short8*)(p + t * 8) = v;
}

// in-place layernorm on fp32 rows of 1024
__global__ __launch_bounds__(256) void k_layernorm(float* __restrict__ y,
                                                   const float* __restrict__ g,
                                                   const float* __restrict__ b) {
    __shared__ float redS[4], redQ[4];
    const long long row = blockIdx.x;
    float* p = y + row * DD;
    const int t = threadIdx.x;
    float4 v = *(float4*)(p + t * 4);
    float s = v.x + v.y + v.z + v.w;
    float q = v.x * v.x + v.y * v.y + v.z * v.z + v.w * v.w;
    s = waveSum(s); q = waveSum(q);
    if ((t & 63) == 0) { redS[t >> 6] = s; redQ[t >> 6] = q; }
    __syncthreads();
    s = (redS[0] + redS[1]) + (redS[2] + redS[3]);
    q = (redQ[0] + redQ[1]) + (redQ[2] + redQ[3]);
    float mu = s * (1.f / DD);
    float var = q * (1.f / DD) - mu * mu;
    float rs = rsqrtf(var + 1e-5f);
    float4 o;
    o.x = (v.x - mu) * rs * g[t * 4 + 0] + b[t * 4 + 0];
    o.y = (v.y - mu) * rs * g[t * 4 + 1] + b[t * 4 + 1];
    o.z = (v.z - mu) * rs * g[t * 4 + 2] + b[t * 4 + 2];
    o.w = (v.w - mu) * rs * g[t * 4 + 3] + b[t * 4 + 3];
    *(float4*)(p + t * 4) = o;
}

// 64x64 LDS-tiled transpose, bf16 -> bf16, per-batch via blockIdx.z
__global__ __launch_bounds__(256) void k_transpose_bf16(const short* __restrict__ in,
                                                        short* __restrict__ out,
                                                        int rows, int cols) {
    __shared__ short tile[64][65];
    const long long boff = (long long)blockIdx.z * rows * cols;
    in += boff; out += boff;
    const int r0 = blockIdx.y * 64, c0 = blockIdx.x * 64;
    const int t = threadIdx.x;
#pragma unroll
    for (int i = 0; i < 16; i++) {
        int lin = i * 256 + t; int lr = lin >> 6, lc = lin & 63;
        tile[lr][lc] = in[(long long)(r0 + lr) * cols + (c0 + lc)];
    }
    __syncthreads();
#pragma unroll
    for (int i = 0; i < 16; i++) {
        int lin = i * 256 + t; int orr = lin >> 6, oc = lin & 63;
        out[(long long)(c0 + orr) * rows + (r0 + oc)] = tile[oc][orr];
    }
}

// 64x64 LDS-tiled transpose, fp32 -> bf16 (for mem_w^T)
__global__ __launch_bounds__(256) void k_transpose_f32_bf16(const float* __restrict__ in,
                                                            short* __restrict__ out,
                                                            int rows, int cols) {
    __shared__ float tile[64][65];
    const int r0 = blockIdx.y * 64, c0 = blockIdx.x * 64;
    const int t = threadIdx.x;
#pragma unroll
    for (int i = 0; i < 16; i++) {
        int lin = i * 256 + t; int lr = lin >> 6, lc = lin & 63;
        tile[lr][lc] = in[(long long)(r0 + lr) * cols + (c0 + lc)];
    }
    __syncthreads();
#pragma unroll
    for (int i = 0; i < 16; i++) {
        int lin = i * 256 + t; int orr = lin >> 6, oc = lin & 63;
        out[(long long)(c0 + orr) * rows + (r0 + oc)] = f2bf(tile[oc][orr]);
    }
}

enum { EPI_SILU, EPI_BIAS, EPI_SCALE, EPI_PLAIN, EPI_GATE, EPI_RESID, EPI_MLOSS };

// ======== R10 GEMM: BK=32, 4 rotating buffers, counted vmcnt + swizzle ====
// Unifies R8's counted-vmcnt pipeline (T4: steady-state vmcnt(8)/(6), never 0
// until the drain ladder) with R9's conflict-free LDS (T2).
// LDS row = 32 shorts = 64 B = 4 chunks of 16 B.  Element (row,c) lives at
// chunk c ^ swz(row), swz(row) = (row&3)^((row>>2)&3).  Both-sides-or-neither
// (rule #21): gload_lds dest LINEAR; global SOURCE chunk pre-swizzled
// (4 threads cover one aligned 64 B row -> fully coalesced); ds_read applies
// the same involution.  Fragment rows = base + rl (base mult of 16) ->
// swz reduces to (rl&3)^((rl>>2)&3): 8 even-lane rows spread 2-per-chunk
// -> 2-way bank aliasing = free (m136).
// Slot safety: STAGE(s+3) -> buf (s-1)&3, issued in slice s after the
// barrier ending slice s-1's reads.  vmcnt at slice end ensures slice s+1
// landed; outstanding = slices s+2, s+3 in flight.

// ---------------- 256x256 tile, 8 waves (2Mx4N), wave tile 128x64 --------
// 2 phases per K32 slice, 16 MFMA each; stage A(s+3) in phase 0, B(s+3) in
// phase 1 (2 gload16 each).  Steady vmcnt(8) = 2 slices x 4 loads.
template <int EPI>
__global__ __launch_bounds__(512) void gemm8p(
    const short* __restrict__ A, int lda, long long sAb,
    const short* __restrict__ W, int ldw, long long sWb,
    void* __restrict__ outv, int ldo, long long sOb,
    const float* __restrict__ bias, long long sBias,
    int K, float scale) {
    constexpr int SB = 16384;          // shorts/buffer: A 8192 + B 8192
    extern __shared__ short lds[];     // 4 * SB * 2B = 128 KiB

    const int z = blockIdx.z;
    A += (long long)z * sAb;
    W += (long long)z * sWb;

    const int tid = threadIdx.x;
    const int wid = tid >> 6, lane = tid & 63;
    const int row0 = blockIdx.y * 256, col0 = blockIdx.x * 256;
    const int wrM = (wid >> 2) * 128, wcN = (wid & 3) * 64;
    const int rl = lane & 15, kcl = lane >> 4;

    f32x4 acc[8][4] = {};

    // staging: 4 threads/row (64 B line), source chunk pre-swizzled
    const int srow = tid >> 2;                                   // 0..127
    const int scswz = (tid & 3) ^ ((srow & 3) ^ ((srow >> 2) & 3));
    long long offA[2], offB[2];
#pragma unroll
    for (int j = 0; j < 2; j++) {
        const int rr = j * 128 + srow;
        offA[j] = (long long)(row0 + rr) * lda + scswz * 8;
        offB[j] = (long long)(col0 + rr) * ldw + scswz * 8;
    }

    auto STAGE_A = [&](int s) {
        short* bp = lds + (s & 3) * SB;
        const short* a = A + (long long)s * 32;
#pragma unroll
        for (int j = 0; j < 2; j++)
            gload16(a + offA[j], bp + (j * 512 + tid) * 8);
    };
    auto STAGE_B = [&](int s) {
        short* bp = lds + (s & 3) * SB + 8192;
        const short* w = W + (long long)s * 32;
#pragma unroll
        for (int j = 0; j < 2; j++)
            gload16(w + offB[j], bp + (j * 512 + tid) * 8);
    };

    const int nk = K >> 5;   // >= 8 for all our K
    STAGE_A(0); STAGE_B(0); STAGE_A(1); STAGE_B(1); STAGE_A(2); STAGE_B(2);
    asm volatile("s_waitcnt vmcnt(8)" ::: "memory");   // slice 0 landed
    __builtin_amdgcn_s_barrier();

    const int rswz = ((rl & 3) ^ ((rl >> 2) & 3));

    for (int s = 0; s < nk; ++s) {
        const short* aB = lds + (s & 3) * SB;
        const short* bB = aB + 8192;
        const bool pf = (s + 3) < nk;
        short8 af[4], bfr[4];

        // ---- phase 0: mi 0..3 ----
#pragma unroll
        for (int mi = 0; mi < 4; mi++)
            af[mi] = *(const short8*)&aB[(wrM + mi * 16 + rl) * 32 + (kcl ^ rswz) * 8];
#pragma unroll
        for (int ni = 0; ni < 4; ni++)
            bfr[ni] = *(const short8*)&bB[(wcN + ni * 16 + rl) * 32 + (kcl ^ rswz) * 8];
        if (pf) STAGE_A(s + 3);
        __builtin_amdgcn_s_barrier();
        asm volatile("s_waitcnt lgkmcnt(0)" ::: "memory");
        __builtin_amdgcn_s_setprio(1);
#pragma unroll
        for (int mi = 0; mi < 4; mi++)
#pragma unroll
            for (int ni = 0; ni < 4; ni++)
                acc[mi][ni] = __builtin_amdgcn_mfma_f32_16x16x32_bf16(
                    af[mi], bfr[ni], acc[mi][ni], 0, 0, 0);
        __builtin_amdgcn_s_setprio(0);
        __builtin_amdgcn_s_barrier();

        // ---- phase 1: mi 4..7 ----
#pragma unroll
        for (int mi = 0; mi < 4; mi++)
            af[mi] = *(const short8*)&aB[(wrM + 64 + mi * 16 + rl) * 32 + (kcl ^ rswz) * 8];
        if (pf) STAGE_B(s + 3);
        __builtin_amdgcn_s_barrier();
        asm volatile("s_waitcnt lgkmcnt(0)" ::: "memory");
        __builtin_amdgcn_s_setprio(1);
#pragma unroll
        for (int mi = 0; mi < 4; mi++)
#pragma unroll
            for (int ni = 0; ni < 4; ni++)
                acc[4 + mi][ni] = __builtin_amdgcn_mfma_f32_16x16x32_bf16(
                    af[mi], bfr[ni], acc[4 + mi][ni], 0, 0, 0);
        __builtin_amdgcn_s_setprio(0);
        // slice s+1 readiness (counted; collective via barrier)
        const int rem = nk - 1 - s;
        if (rem >= 3)      asm volatile("s_waitcnt vmcnt(8)" ::: "memory");
        else if (rem == 2) asm volatile("s_waitcnt vmcnt(4)" ::: "memory");
        else if (rem == 1) asm volatile("s_waitcnt vmcnt(0)" ::: "memory");
        __builtin_amdgcn_s_barrier();
    }

    // epilogue: C/D layout col=lane&15, row=(lane>>4)*4+r  [m89/m91-verified]
    const int lr4 = (lane >> 4) * 4;
    float bcol[4];
    if constexpr (EPI == EPI_SILU || EPI == EPI_BIAS) {
        const float* bz = bias + (long long)z * sBias;
#pragma unroll
        for (int ni = 0; ni < 4; ni++) bcol[ni] = bz[col0 + wcN + ni * 16 + rl];
    }
    short* op = (short*)outv + (long long)z * sOb;
#pragma unroll
    for (int mi = 0; mi < 8; mi++) {
#pragma unroll
        for (int ni = 0; ni < 4; ni++) {
            const int gc = col0 + wcN + ni * 16 + rl;
#pragma unroll
            for (int r = 0; r < 4; r++) {
                const int gr = row0 + wrM + mi * 16 + lr4 + r;
                float v = acc[mi][ni][r];
                if constexpr (EPI == EPI_SILU) {
                    v += bcol[ni];
                    v = v / (1.f + __expf(-v));
                } else if constexpr (EPI == EPI_BIAS) {
                    v += bcol[ni];
                } else if constexpr (EPI == EPI_SCALE) {
                    v *= scale;
                }
                op[(long long)gr * ldo + gc] = f2bf(v);
            }
        }
    }
}

// ---------------- 128x256 tile, 8 waves (2Mx4N), wave tile 64x64 ---------
// 1 phase per K32 slice (16 MFMA); stage A+B(s+3) (3 loads) in the phase.
// Steady vmcnt(6) = 2 slices x 3 loads; ladder 6 -> 3 -> 0.
template <int EPI>
__global__ __launch_bounds__(512) void gemm128(
    const short* __restrict__ A, int lda, long long sAb,
    const short* __restrict__ W, int ldw, long long sWb,
    void* __restrict__ outv, int ldo, long long sOb,
    const float* __restrict__ bias, long long sBias,
    const void* __restrict__ aux,
    int K, float scale, float* __restrict__ lossOut) {
    constexpr int ASH = 4096;           // A slice shorts (128 rows x 32)
    constexpr int SB  = ASH + 8192;     // 12288 shorts = 24 KiB/buffer
    extern __shared__ short lds[];      // 4 * SB * 2B = 96 KiB

    const int z = blockIdx.z;
    A += (long long)z * sAb;
    W += (long long)z * sWb;

    const int tid = threadIdx.x;
    const int wid = tid >> 6, lane = tid & 63;
    const int row0 = blockIdx.y * 128, col0 = blockIdx.x * 256;
    const int wrM = (wid >> 2) * 64, wcN = (wid & 3) * 64;
    const int rl = lane & 15, kcl = lane >> 4;

    f32x4 acc[4][4] = {};

    const int srow = tid >> 2;                                   // 0..127
    const int scswz = (tid & 3) ^ ((srow & 3) ^ ((srow >> 2) & 3));
    long long offA, offB[2];
    offA = (long long)(row0 + srow) * lda + scswz * 8;
#pragma unroll
    for (int j = 0; j < 2; j++)
        offB[j] = (long long)(col0 + j * 128 + srow) * ldw + scswz * 8;

    auto STAGE = [&](int s) {
        short* bp = lds + (s & 3) * SB;
        gload16(A + (long long)s * 32 + offA, bp + tid * 8);
        const short* w = W + (long long)s * 32;
#pragma unroll
        for (int j = 0; j < 2; j++)
            gload16(w + offB[j], bp + ASH + (j * 512 + tid) * 8);
    };

    const int nk = K >> 5;
    STAGE(0); STAGE(1); STAGE(2);
    asm volatile("s_waitcnt vmcnt(6)" ::: "memory");   // slice 0 landed
    __builtin_amdgcn_s_barrier();

    const int rswz = ((rl & 3) ^ ((rl >> 2) & 3));

    for (int s = 0; s < nk; ++s) {
        const short* aB = lds + (s & 3) * SB;
        const short* bB = aB + ASH;
        short8 af[4], bfr[4];
#pragma unroll
        for (int mi = 0; mi < 4; mi++)
            af[mi] = *(const short8*)&aB[(wrM + mi * 16 + rl) * 32 + (kcl ^ rswz) * 8];
#pragma unroll
        for (int ni = 0; ni < 4; ni++)
            bfr[ni] = *(const short8*)&bB[(wcN + ni * 16 + rl) * 32 + (kcl ^ rswz) * 8];
        if (s + 3 < nk) STAGE(s + 3);
        __builtin_amdgcn_s_barrier();
        asm volatile("s_waitcnt lgkmcnt(0)" ::: "memory");
        __builtin_amdgcn_s_setprio(1);
#pragma unroll
        for (int mi = 0; mi < 4; mi++)
#pragma unroll
            for (int ni = 0; ni < 4; ni++)
                acc[mi][ni] = __builtin_amdgcn_mfma_f32_16x16x32_bf16(
                    af[mi], bfr[ni], acc[mi][ni], 0, 0, 0);
        __builtin_amdgcn_s_setprio(0);
        const int rem = nk - 1 - s;
        if (rem >= 3)      asm volatile("s_waitcnt vmcnt(6)" ::: "memory");
        else if (rem == 2) asm volatile("s_waitcnt vmcnt(3)" ::: "memory");
        else if (rem == 1) asm volatile("s_waitcnt vmcnt(0)" ::: "memory");
        __builtin_amdgcn_s_barrier();
    }

    // epilogue
    const int lr4 = (lane >> 4) * 4;
    float bcol[4];
    if constexpr (EPI == EPI_SILU || EPI == EPI_BIAS || EPI == EPI_GATE || EPI == EPI_RESID) {
        const float* bz = bias + (long long)z * sBias;
#pragma unroll
        for (int ni = 0; ni < 4; ni++) bcol[ni] = bz[col0 + wcN + ni * 16 + rl];
    }
    float lsum = 0.f;
#pragma unroll
    for (int mi = 0; mi < 4; mi++) {
#pragma unroll
        for (int ni = 0; ni < 4; ni++) {
            const int gc = col0 + wcN + ni * 16 + rl;
#pragma unroll
            for (int r = 0; r < 4; r++) {
                const int gr = row0 + wrM + mi * 16 + lr4 + r;
                const long long oi = (long long)gr * ldo + gc;
                float v = acc[mi][ni][r];
                if constexpr (EPI == EPI_SILU) {
                    v += bcol[ni];
                    v = v / (1.f + __expf(-v));
                    ((short*)outv + (long long)z * sOb)[oi] = f2bf(v);
                } else if constexpr (EPI == EPI_BIAS) {
                    ((short*)outv + (long long)z * sOb)[oi] = f2bf(v + bcol[ni]);
                } else if constexpr (EPI == EPI_SCALE) {
                    ((short*)outv + (long long)z * sOb)[oi] = f2bf(v * scale);
                } else if constexpr (EPI == EPI_PLAIN) {
                    ((short*)outv + (long long)z * sOb)[oi] = f2bf(v);
                } else if constexpr (EPI == EPI_GATE) {
                    float g = 1.f / (1.f + __expf(-(v + bcol[ni])));
                    float a = bf2f(((const short*)aux)[oi]);
                    ((short*)outv)[oi] = f2bf(g * a);
                } else if constexpr (EPI == EPI_RESID) {
                    ((float*)outv)[oi] = v + bcol[ni] + ((const float*)aux)[oi];
                } else {  // EPI_MLOSS
                    float dd = v - bf2f(((const short*)aux)[oi]);
                    lsum += dd * dd;
                }
            }
        }
    }
    if constexpr (EPI == EPI_MLOSS) {
        lsum = waveSum(lsum);
        if (lane == 0) atomicAdd(lossOut, lsum * scale);
    }
}

// ---------------- host ----------------

extern "C" void kernel_launch(void* const* d_in, const int* in_sizes, int n_in,
                              void* d_out, int out_size, void* d_ws, size_t ws_size,
                              hipStream_t stream) {
    const float* x    = (const float*)d_in[0];
    const float* wq   = (const float*)d_in[1];
    const float* bq   = (const float*)d_in[2];
    const float* wk   = (const float*)d_in[3];
    const float* bk   = (const float*)d_in[4];
    const float* wvw  = (const float*)d_in[5];
    const float* bvv  = (const float*)d_in[6];
    const float* dwq  = (const float*)d_in[7];
    const float* dwqb = (const float*)d_in[8];
    const float* pwq  = (const float*)d_in[9];
    const float* pwqb = (const float*)d_in[10];
    const float* dwk  = (const float*)d_in[11];
    const float* dwkb = (const float*)d_in[12];
    const float* pwk  = (const float*)d_in[13];
    const float* pwkb = (const float*)d_in[14];
    const float* dwv  = (const float*)d_in[15];
    const float* dwvb = (const float*)d_in[16];
    const float* pwv  = (const float*)d_in[17];
    const float* pwvb = (const float*)d_in[18];
    const float* wg   = (const float*)d_in[19];
    const float* bg   = (const float*)d_in[20];
    const float* wo   = (const float*)d_in[21];
    const float* bo   = (const float*)d_in[22];
    const float* memw = (const float*)d_in[23];
    const float* lng  = (const float*)d_in[24];
    const float* lnb  = (const float*)d_in[25];

    float* out = (float*)d_out;
    float* loss = out + BLD;

    char* base = (char*)d_ws;
    size_t off = 0;
    auto take = [&](size_t n) -> char* {
        char* p = base + off;
        off += (n + 255) & ~(size_t)255;
        return p;
    };
    const size_t WB = (size_t)DD * DD * 2;  // 2 MB bf16 weight
    const size_t XB = (size_t)BLD * 2;      // 16.78 MB bf16 activation
    short* Wqkv = (short*)take(3 * WB);     // concat [3072][1024]
    short* Pqkv = (short*)take(3 * WB);     // concat pointwise weights
    short* Wgb  = (short*)take(WB);
    short* Wob  = (short*)take(WB);
    short* MwT  = (short*)take(WB);
    float* bqkv = (float*)take(3072 * 4);
    float* bpw  = (float*)take(3072 * 4);
    short* xb   = (short*)take(XB);         // x bf16; reused as attn_out later
    short* pre  = (short*)take(3 * XB);     // QKV silu [8192][3072]; reused as qb/kb/vb
    short* post = (short*)take(3 * XB);     // conv out [8192][3072]; reused as scores+VT, gated

    short* qb = pre;
    short* kb = pre + BLD;
    short* vb = pre + 2 * BLD;
    short* scores = post;            // [4][2048][2048] bf16 = 2*BLD shorts
    short* VT = post + 2 * BLD;      // [4][1024][2048]
    short* aob = xb;                 // attn_out bf16 (xb dead after QKV GEMM)
    short* gated = post;             // gated bf16 (scores/VT dead after attn@V)
    (void)ws_size; (void)in_sizes; (void)n_in; (void)out_size;

    const long long sLD = (long long)LL * DD;   // 2048*1024
    const long long sLLb = (long long)LL * LL;  // 2048*2048
    const size_t LDS8P  = 4 * 16384 * 2;   // 128 KiB
    const size_t LDS128 = 4 * 12288 * 2;   //  96 KiB

    k_zero1<<<1, 1, 0, stream>>>(loss);
    k_wcat<<<4096, 256, 0, stream>>>(wq, wk, wvw, pwq, pwk, pwv, wg, wo,
                                     Wqkv, Pqkv, Wgb, Wob);
    k_biascat<<<24, 256, 0, stream>>>(bq, bk, bvv, pwqb, pwkb, pwvb, bqkv, bpw);
    k_transpose_f32_bf16<<<dim3(16, 16, 1), 256, 0, stream>>>(memw, MwT, DD, DD);
    k_f32_to_bf16<<<4096, 256, 0, stream>>>(x, xb, (int)(BLD / 8));

    // fused QKV: silu(x @ [wq;wk;wv]^T + [bq;bk;bv]) -> pre [8192][3072]
    gemm8p<EPI_SILU><<<dim3(12, 32, 1), 512, LDS8P, stream>>>(
        xb, 1024, 0, Wqkv, 1024, 0, pre, 3072, 0, bqkv, 0, 1024, 0.f);

    // fused depthwise conv: pre -> post (8 L-rows per thread, vector weights)
    k_dwconv3b<<<1536, 256, 0, stream>>>(pre, dwq, dwk, dwv, dwqb, dwkb, dwvb, post);

    // batched pointwise: z=3 branches; A = post columns z*1024.., out -> qb/kb/vb
    gemm8p<EPI_BIAS><<<dim3(4, 32, 3), 512, LDS8P, stream>>>(
        post, 3072, 1024, Pqkv, 1024, (long long)DD * DD, qb, 1024, BLD,
        bpw, 1024, 1024, 0.f);

    // normalize qb AND kb in one launch (contiguous rows of pre) + V^T
    k_l2norm<<<16384, 256, 0, stream>>>(qb);
    k_transpose_bf16<<<dim3(16, 32, 4), 256, 0, stream>>>(vb, VT, 2048, 1024);

    // scores = Qn @ Kn^T / 32  (per batch)
    gemm8p<EPI_SCALE><<<dim3(8, 8, 4), 512, LDS8P, stream>>>(
        qb, 1024, sLD, kb, 1024, sLD, scores, 2048, sLLb,
        nullptr, 0, 1024, 0.03125f);
    k_softmax<<<8192, 256, 0, stream>>>(scores);

    // attn_out = attn @ V  (W = V^T[d, l])
    gemm128<EPI_PLAIN><<<dim3(4, 16, 4), 512, LDS128, stream>>>(
        scores, 2048, sLLb, VT, 2048, sLD, aob, 1024, sLD,
        nullptr, 0, nullptr, 2048, 0.f, nullptr);

    // gated = sigmoid(attn_out @ wg^T + bg) * attn_out
    gemm128<EPI_GATE><<<dim3(4, 64, 1), 512, LDS128, stream>>>(
        aob, 1024, 0, Wgb, 1024, 0, gated, 1024, 0, bg, 0, aob, 1024, 0.f, nullptr);

    // out = gated @ wo^T + bo + x ; then LN in-place
    gemm128<EPI_RESID><<<dim3(4, 64, 1), 512, LDS128, stream>>>(
        gated, 1024, 0, Wob, 1024, 0, out, 1024, 0, bo, 0, x, 1024, 0.f, nullptr);
    k_layernorm<<<8192, 256, 0, stream>>>(out, lng, lnb);

    // mem_loss = mean((Kn @ mem_w - V)^2)
    gemm128<EPI_MLOSS><<<dim3(4, 64, 1), 512, LDS128, stream>>>(
        kb, 1024, 0, MwT, 1024, 0, nullptr, 1024, 0, nullptr, 0, vb,
        1024, 1.f / (float)BLD, loss);
}

// Round 11
// 402.795 us; speedup vs baseline: 1.1933x; 1.1933x over previous
//
#include <hip/hip_runtime.h>
#include <stdint.h>

typedef __attribute__((ext_vector_type(8))) short short8;
typedef __attribute__((ext_vector_type(4))) short short4v;
typedef __attribute__((ext_vector_type(4))) float f32x4;

#define DEV static __device__ __forceinline__

static constexpr int LL = 2048;
static constexpr int DD = 1024;
static constexpr long long BLD = 8388608LL; // 4*2048*1024

DEV short f2bf(float f) {
    uint32_t u = __builtin_bit_cast(uint32_t, f);
    u += 0x7fffu + ((u >> 16) & 1u);   // RNE
    return (short)(u >> 16);
}
DEV float bf2f(short s) {
    uint32_t u = ((uint32_t)(uint16_t)s) << 16;
    return __builtin_bit_cast(float, u);
}

DEV float waveSum(float v) {
#pragma unroll
    for (int o = 32; o; o >>= 1) v += __shfl_down(v, o);
    return v;
}
DEV float waveMax(float v) {
#pragma unroll
    for (int o = 32; o; o >>= 1) v = fmaxf(v, __shfl_down(v, o));
    return v;
}

DEV void gload16(const void* g, void* l) {
    __builtin_amdgcn_global_load_lds(
        (const __attribute__((address_space(1))) uint32_t*)(uintptr_t)g,
        (__attribute__((address_space(3))) uint32_t*)(uintptr_t)l,
        16, 0, 0);
}

// ---------------- elementwise / reduction kernels ----------------

__global__ __launch_bounds__(256) void k_zero1(float* p) {
    if (threadIdx.x == 0) *p = 0.f;
}

__global__ __launch_bounds__(256) void k_f32_to_bf16(const float* __restrict__ in,
                                                     short* __restrict__ out, int n8) {
    int i = blockIdx.x * 256 + threadIdx.x;
    if (i >= n8) return;
    const float4* p = (const float4*)(in + (long long)i * 8);
    float4 a = p[0], b = p[1];
    short8 o;
    o[0] = f2bf(a.x); o[1] = f2bf(a.y); o[2] = f2bf(a.z); o[3] = f2bf(a.w);
    o[4] = f2bf(b.x); o[5] = f2bf(b.y); o[6] = f2bf(b.z); o[7] = f2bf(b.w);
    *(short8*)(out + (long long)i * 8) = o;
}

// convert 8 D*D fp32 weights to bf16 destinations in one launch (512 blocks each)
__global__ __launch_bounds__(256) void k_wcat(
    const float* wq, const float* wk, const float* wv,
    const float* pq, const float* pk, const float* pv,
    const float* wg, const float* wo,
    short* Wqkv, short* Pqkv, short* Wg, short* Wo) {
    const int bid = blockIdx.x;            // 4096 blocks
    const int w = bid >> 9;                // which weight
    const long long i = (long long)((bid & 511) * 256 + threadIdx.x) * 8;
    const float* src; short* dst;
    switch (w) {
        case 0: src = wq; dst = Wqkv;                break;
        case 1: src = wk; dst = Wqkv + 1048576;      break;
        case 2: src = wv; dst = Wqkv + 2097152;      break;
        case 3: src = pq; dst = Pqkv;                break;
        case 4: src = pk; dst = Pqkv + 1048576;      break;
        case 5: src = pv; dst = Pqkv + 2097152;      break;
        case 6: src = wg; dst = Wg;                  break;
        default: src = wo; dst = Wo;                 break;
    }
    const float4* p = (const float4*)(src + i);
    float4 a = p[0], b = p[1];
    short8 o;
    o[0] = f2bf(a.x); o[1] = f2bf(a.y); o[2] = f2bf(a.z); o[3] = f2bf(a.w);
    o[4] = f2bf(b.x); o[5] = f2bf(b.y); o[6] = f2bf(b.z); o[7] = f2bf(b.w);
    *(short8*)(dst + i) = o;
}

// concat 6 length-1024 fp32 bias vectors into bqkv[3072] and bpw[3072]
__global__ __launch_bounds__(256) void k_biascat(
    const float* bq, const float* bk, const float* bv,
    const float* pq, const float* pk, const float* pv,
    float* bqkv, float* bpw) {
    const int idx = blockIdx.x * 256 + threadIdx.x;  // 24 blocks -> 6144
    const int sel = idx >> 10, j = idx & 1023;
    const float* s;
    switch (sel) {
        case 0: s = bq; break; case 1: s = bk; break; case 2: s = bv; break;
        case 3: s = pq; break; case 4: s = pk; break; default: s = pv; break;
    }
    float v = s[j];
    if (sel < 3) bqkv[sel * 1024 + j] = v;
    else         bpw[(sel - 3) * 1024 + j] = v;
}

// fused depthwise conv over L (k=3, pad 1) + bias, all 3 branches.
// Each thread: one 8-channel chunk x 8 consecutive L rows (register sliding
// window); weights as 6x float4 + 2x float4 -> 26 coalesced VMEM/8 rows.
__global__ __launch_bounds__(256) void k_dwconv3b(const short* __restrict__ in,
                                                  const float* __restrict__ dwq,
                                                  const float* __restrict__ dwk,
                                                  const float* __restrict__ dwv,
                                                  const float* __restrict__ dbq,
                                                  const float* __restrict__ dbk,
                                                  const float* __restrict__ dbv,
                                                  short* __restrict__ outp) {
    const int idx = blockIdx.x * 256 + threadIdx.x;  // 3*4*256*128 = 393216
    const int d8 = idx & 127;
    const int lc = (idx >> 7) & 255;
    const int b  = (idx >> 15) & 3;
    const int br = idx >> 17;                         // uniform per block
    const float* dw = (br == 0) ? dwq : (br == 1) ? dwk : dwv;
    const float* db = (br == 0) ? dbq : (br == 1) ? dbk : dbv;

    float w[24], bb[8];
    {
        const float4* wp = (const float4*)(dw + d8 * 24);
#pragma unroll
        for (int i = 0; i < 6; i++) {
            float4 t = wp[i];
            w[i * 4 + 0] = t.x; w[i * 4 + 1] = t.y;
            w[i * 4 + 2] = t.z; w[i * 4 + 3] = t.w;
        }
        const float4* bp = (const float4*)(db + d8 * 8);
        float4 t0 = bp[0], t1 = bp[1];
        bb[0] = t0.x; bb[1] = t0.y; bb[2] = t0.z; bb[3] = t0.w;
        bb[4] = t1.x; bb[5] = t1.y; bb[6] = t1.z; bb[7] = t1.w;
    }

    const int l0 = lc * 8;
    const long long base = ((long long)(b * LL + l0)) * 3072 + br * 1024 + d8 * 8;
    short8 xr[10];
#pragma unroll
    for (int i = 0; i < 10; i++) {
        const int l = l0 - 1 + i;
        if (l >= 0 && l < LL) xr[i] = *(const short8*)(in + base + (long long)(i - 1) * 3072);
        else { short8 z = {0, 0, 0, 0, 0, 0, 0, 0}; xr[i] = z; }
    }
#pragma unroll
    for (int j = 0; j < 8; j++) {
        short8 o;
#pragma unroll
        for (int c = 0; c < 8; c++) {
            float v = bb[c] + w[c * 3 + 0] * bf2f(xr[j][c])
                            + w[c * 3 + 1] * bf2f(xr[j + 1][c])
                            + w[c * 3 + 2] * bf2f(xr[j + 2][c]);
            o[c] = f2bf(v);
        }
        *(short8*)(outp + base + (long long)j * 3072) = o;
    }
}

// in-place row L2 normalize, row = blockIdx.x, D=1024, 256 thr * 4
__global__ __launch_bounds__(256) void k_l2norm(short* __restrict__ xp) {
    __shared__ float red[4];
    const long long row = blockIdx.x;
    short* p = xp + row * DD;
    const int t = threadIdx.x;
    short4v v = *(short4v*)(p + t * 4);
    float f0 = bf2f(v[0]), f1 = bf2f(v[1]), f2 = bf2f(v[2]), f3 = bf2f(v[3]);
    float ss = f0 * f0 + f1 * f1 + f2 * f2 + f3 * f3;
    ss = waveSum(ss);
    if ((t & 63) == 0) red[t >> 6] = ss;
    __syncthreads();
    ss = (red[0] + red[1]) + (red[2] + red[3]);
    float s = 1.f / fmaxf(sqrtf(ss), 1e-12f);
    v[0] = f2bf(f0 * s); v[1] = f2bf(f1 * s); v[2] = f2bf(f2 * s); v[3] = f2bf(f3 * s);
    *(short4v*)(p + t * 4) = v;
}

// in-place row softmax, width 2048 bf16, row = blockIdx.x
__global__ __launch_bounds__(256) void k_softmax(short* __restrict__ sp) {
    __shared__ float redM[4], redS[4];
    const long long row = blockIdx.x;
    short* p = sp + row * 2048;
    const int t = threadIdx.x;
    short8 v = *(short8*)(p + t * 8);
    float f[8];
    float m = -3.0e38f;
#pragma unroll
    for (int j = 0; j < 8; j++) { f[j] = bf2f(v[j]); m = fmaxf(m, f[j]); }
    m = waveMax(m);
    if ((t & 63) == 0) redM[t >> 6] = m;
    __syncthreads();
    m = fmaxf(fmaxf(redM[0], redM[1]), fmaxf(redM[2], redM[3]));
    float s = 0.f;
#pragma unroll
    for (int j = 0; j < 8; j++) { f[j] = __expf(f[j] - m); s += f[j]; }
    s = waveSum(s);
    if ((t & 63) == 0) redS[t >> 6] = s;
    __syncthreads();
    s = (redS[0] + redS[1]) + (redS[2] + redS[3]);
    float inv = 1.f / s;
#pragma unroll
    for (int j = 0; j < 8; j++) v[j] = f2bf(f[j] * inv);
    *(short8*)(p + t * 8) = v;
}

// in-place layernorm on fp32 rows of 1024
__global__ __launch_bounds__(256) void k_layernorm(float* __restrict__ y,
                                                   const float* __restrict__ g,
                                                   const float* __restrict__ b) {
    __shared__ float redS[4], redQ[4];
    const long long row = blockIdx.x;
    float* p = y + row * DD;
    const int t = threadIdx.x;
    float4 v = *(float4*)(p + t * 4);
    float s = v.x + v.y + v.z + v.w;
    float q = v.x * v.x + v.y * v.y + v.z * v.z + v.w * v.w;
    s = waveSum(s); q = waveSum(q);
    if ((t & 63) == 0) { redS[t >> 6] = s; redQ[t >> 6] = q; }
    __syncthreads();
    s = (redS[0] + redS[1]) + (redS[2] + redS[3]);
    q = (redQ[0] + redQ[1]) + (redQ[2] + redQ[3]);
    float mu = s * (1.f / DD);
    float var = q * (1.f / DD) - mu * mu;
    float rs = rsqrtf(var + 1e-5f);
    float4 o;
    o.x = (v.x - mu) * rs * g[t * 4 + 0] + b[t * 4 + 0];
    o.y = (v.y - mu) * rs * g[t * 4 + 1] + b[t * 4 + 1];
    o.z = (v.z - mu) * rs * g[t * 4 + 2] + b[t * 4 + 2];
    o.w = (v.w - mu) * rs * g[t * 4 + 3] + b[t * 4 + 3];
    *(float4*)(p + t * 4) = o;
}

// 64x64 LDS-tiled transpose, bf16 -> bf16, per-batch via blockIdx.z
__global__ __launch_bounds__(256) void k_transpose_bf16(const short* __restrict__ in,
                                                        short* __restrict__ out,
                                                        int rows, int cols) {
    __shared__ short tile[64][65];
    const long long boff = (long long)blockIdx.z * rows * cols;
    in += boff; out += boff;
    const int r0 = blockIdx.y * 64, c0 = blockIdx.x * 64;
    const int t = threadIdx.x;
#pragma unroll
    for (int i = 0; i < 16; i++) {
        int lin = i * 256 + t; int lr = lin >> 6, lc = lin & 63;
        tile[lr][lc] = in[(long long)(r0 + lr) * cols + (c0 + lc)];
    }
    __syncthreads();
#pragma unroll
    for (int i = 0; i < 16; i++) {
        int lin = i * 256 + t; int orr = lin >> 6, oc = lin & 63;
        out[(long long)(c0 + orr) * rows + (r0 + oc)] = tile[oc][orr];
    }
}

// 64x64 LDS-tiled transpose, fp32 -> bf16 (for mem_w^T)
__global__ __launch_bounds__(256) void k_transpose_f32_bf16(const float* __restrict__ in,
                                                            short* __restrict__ out,
                                                            int rows, int cols) {
    __shared__ float tile[64][65];
    const int r0 = blockIdx.y * 64, c0 = blockIdx.x * 64;
    const int t = threadIdx.x;
#pragma unroll
    for (int i = 0; i < 16; i++) {
        int lin = i * 256 + t; int lr = lin >> 6, lc = lin & 63;
        tile[lr][lc] = in[(long long)(r0 + lr) * cols + (c0 + lc)];
    }
    __syncthreads();
#pragma unroll
    for (int i = 0; i < 16; i++) {
        int lin = i * 256 + t; int orr = lin >> 6, oc = lin & 63;
        out[(long long)(c0 + orr) * rows + (r0 + oc)] = f2bf(tile[oc][orr]);
    }
}

enum { EPI_SILU, EPI_BIAS, EPI_SCALE, EPI_PLAIN, EPI_GATE, EPI_RESID, EPI_MLOSS };

// ======== R11 unified GEMM: 128x128 tile, BK=64, single buffer, 4 blk/CU ==
// m97 structure scaled to BK=64: per K-tile {STAGE; vmcnt(0); barrier;
// ds_reads + MFMA; barrier}.  NO intra-block prefetch — latency hiding comes
// from 4 co-resident blocks/CU (m114: implicit wave-level overlap; m97's
// 874 TF ran ~3 blk/CU with this exact shape).  LDS = 32 KiB (A 16K + B 16K),
// 256 threads (4 waves as 2Mx2N, wave tile 64x64), __launch_bounds__(256,4)
// caps VGPR <=128 so 16 waves/CU fit (m69 occupancy steps).
// Swizzle: R9-PROVEN conflict-free geometry — row = 64 shorts = 128 B =
// 8 chunks of 16 B; element chunk c at physical chunk c ^ (row&7).
// Both-sides-or-neither (rule #21): gload_lds dest LINEAR, global SOURCE
// chunk pre-swizzled (8 thr cover one aligned 128 B row -> fully coalesced),
// ds_read applies the same involution.  (64 B-row variants measured 4.7M
// conflicts in R8/R10 — do not regress to them.)
// ks0 processed fully before ks1 to keep live fragments at 8 (VGPR <=128).
template <int EPI>
__global__ __launch_bounds__(256, 4) void gemm(
    const short* __restrict__ A, int lda, long long sAb,
    const short* __restrict__ W, int ldw, long long sWb,
    void* __restrict__ outv, int ldo, long long sOb,
    const float* __restrict__ bias, long long sBias,
    const void* __restrict__ aux,
    int K, float scale, float* __restrict__ lossOut) {
    __shared__ short lds[16384];       // A 8192 + B 8192 shorts = 32 KiB

    const int z = blockIdx.z;
    A += (long long)z * sAb;
    W += (long long)z * sWb;

    const int tid = threadIdx.x;
    const int wid = tid >> 6, lane = tid & 63;
    const int row0 = blockIdx.y * 128, col0 = blockIdx.x * 128;
    const int wrM = (wid >> 1) * 64, wcN = (wid & 1) * 64;
    const int rl = lane & 15, kcl = lane >> 4;

    f32x4 acc[4][4] = {};

    // staging: 8 threads/row (128 B line), source chunk pre-swizzled
    const int srow = tid >> 3;                       // 0..31
    const int cswz = (tid & 7) ^ (srow & 7);
    long long offA[4], offB[4];
#pragma unroll
    for (int j = 0; j < 4; j++) {
        const int rr = j * 32 + srow;                // row&7 == srow&7
        offA[j] = (long long)(row0 + rr) * lda + cswz * 8;
        offB[j] = (long long)(col0 + rr) * ldw + cswz * 8;
    }

    const int nk = K >> 6;
    const int swz0 = (kcl ^ (rl & 7)) * 8;
    const int swz1 = ((kcl + 4) ^ (rl & 7)) * 8;

    for (int t = 0; t < nk; ++t) {
        const short* a = A + (long long)t * 64;
        const short* w = W + (long long)t * 64;
#pragma unroll
        for (int j = 0; j < 4; j++)
            gload16(a + offA[j], lds + (j * 256 + tid) * 8);
#pragma unroll
        for (int j = 0; j < 4; j++)
            gload16(w + offB[j], lds + 8192 + (j * 256 + tid) * 8);
        asm volatile("s_waitcnt vmcnt(0)" ::: "memory");
        __builtin_amdgcn_s_barrier();

        short8 af[4], bfr[4];
        // ---- ks = 0 ----
#pragma unroll
        for (int mi = 0; mi < 4; mi++)
            af[mi] = *(const short8*)&lds[(wrM + mi * 16 + rl) * 64 + swz0];
#pragma unroll
        for (int ni = 0; ni < 4; ni++)
            bfr[ni] = *(const short8*)&lds[8192 + (wcN + ni * 16 + rl) * 64 + swz0];
        __builtin_amdgcn_s_setprio(1);
#pragma unroll
        for (int mi = 0; mi < 4; mi++)
#pragma unroll
            for (int ni = 0; ni < 4; ni++)
                acc[mi][ni] = __builtin_amdgcn_mfma_f32_16x16x32_bf16(
                    af[mi], bfr[ni], acc[mi][ni], 0, 0, 0);
        __builtin_amdgcn_s_setprio(0);
        // ---- ks = 1 ----
#pragma unroll
        for (int mi = 0; mi < 4; mi++)
            af[mi] = *(const short8*)&lds[(wrM + mi * 16 + rl) * 64 + swz1];
#pragma unroll
        for (int ni = 0; ni < 4; ni++)
            bfr[ni] = *(const short8*)&lds[8192 + (wcN + ni * 16 + rl) * 64 + swz1];
        __builtin_amdgcn_s_setprio(1);
#pragma unroll
        for (int mi = 0; mi < 4; mi++)
#pragma unroll
            for (int ni = 0; ni < 4; ni++)
                acc[mi][ni] = __builtin_amdgcn_mfma_f32_16x16x32_bf16(
                    af[mi], bfr[ni], acc[mi][ni], 0, 0, 0);
        __builtin_amdgcn_s_setprio(0);
        __builtin_amdgcn_s_barrier();    // all reads of tile t done before t+1 stages
    }

    // epilogue: C/D layout col=lane&15, row=(lane>>4)*4+r  [m89/m91-verified]
    const int lr4 = (lane >> 4) * 4;
    float bcol[4];
    if constexpr (EPI == EPI_SILU || EPI == EPI_BIAS || EPI == EPI_GATE || EPI == EPI_RESID) {
        const float* bz = bias + (long long)z * sBias;
#pragma unroll
        for (int ni = 0; ni < 4; ni++) bcol[ni] = bz[col0 + wcN + ni * 16 + rl];
    }
    float lsum = 0.f;
#pragma unroll
    for (int mi = 0; mi < 4; mi++) {
#pragma unroll
        for (int ni = 0; ni < 4; ni++) {
            const int gc = col0 + wcN + ni * 16 + rl;
#pragma unroll
            for (int r = 0; r < 4; r++) {
                const int gr = row0 + wrM + mi * 16 + lr4 + r;
                const long long oi = (long long)gr * ldo + gc;
                float v = acc[mi][ni][r];
                if constexpr (EPI == EPI_SILU) {
                    v += bcol[ni];
                    v = v / (1.f + __expf(-v));
                    ((short*)outv + (long long)z * sOb)[oi] = f2bf(v);
                } else if constexpr (EPI == EPI_BIAS) {
                    ((short*)outv + (long long)z * sOb)[oi] = f2bf(v + bcol[ni]);
                } else if constexpr (EPI == EPI_SCALE) {
                    ((short*)outv + (long long)z * sOb)[oi] = f2bf(v * scale);
                } else if constexpr (EPI == EPI_PLAIN) {
                    ((short*)outv + (long long)z * sOb)[oi] = f2bf(v);
                } else if constexpr (EPI == EPI_GATE) {
                    float g = 1.f / (1.f + __expf(-(v + bcol[ni])));
                    float a = bf2f(((const short*)aux)[oi]);
                    ((short*)outv)[oi] = f2bf(g * a);
                } else if constexpr (EPI == EPI_RESID) {
                    ((float*)outv)[oi] = v + bcol[ni] + ((const float*)aux)[oi];
                } else {  // EPI_MLOSS
                    float dd = v - bf2f(((const short*)aux)[oi]);
                    lsum += dd * dd;
                }
            }
        }
    }
    if constexpr (EPI == EPI_MLOSS) {
        lsum = waveSum(lsum);
        if (lane == 0) atomicAdd(lossOut, lsum * scale);
    }
}

// ---------------- host ----------------

extern "C" void kernel_launch(void* const* d_in, const int* in_sizes, int n_in,
                              void* d_out, int out_size, void* d_ws, size_t ws_size,
                              hipStream_t stream) {
    const float* x    = (const float*)d_in[0];
    const float* wq   = (const float*)d_in[1];
    const float* bq   = (const float*)d_in[2];
    const float* wk   = (const float*)d_in[3];
    const float* bk   = (const float*)d_in[4];
    const float* wvw  = (const float*)d_in[5];
    const float* bvv  = (const float*)d_in[6];
    const float* dwq  = (const float*)d_in[7];
    const float* dwqb = (const float*)d_in[8];
    const float* pwq  = (const float*)d_in[9];
    const float* pwqb = (const float*)d_in[10];
    const float* dwk  = (const float*)d_in[11];
    const float* dwkb = (const float*)d_in[12];
    const float* pwk  = (const float*)d_in[13];
    const float* pwkb = (const float*)d_in[14];
    const float* dwv  = (const float*)d_in[15];
    const float* dwvb = (const float*)d_in[16];
    const float* pwv  = (const float*)d_in[17];
    const float* pwvb = (const float*)d_in[18];
    const float* wg   = (const float*)d_in[19];
    const float* bg   = (const float*)d_in[20];
    const float* wo   = (const float*)d_in[21];
    const float* bo   = (const float*)d_in[22];
    const float* memw = (const float*)d_in[23];
    const float* lng  = (const float*)d_in[24];
    const float* lnb  = (const float*)d_in[25];

    float* out = (float*)d_out;
    float* loss = out + BLD;

    char* base = (char*)d_ws;
    size_t off = 0;
    auto take = [&](size_t n) -> char* {
        char* p = base + off;
        off += (n + 255) & ~(size_t)255;
        return p;
    };
    const size_t WB = (size_t)DD * DD * 2;  // 2 MB bf16 weight
    const size_t XB = (size_t)BLD * 2;      // 16.78 MB bf16 activation
    short* Wqkv = (short*)take(3 * WB);     // concat [3072][1024]
    short* Pqkv = (short*)take(3 * WB);     // concat pointwise weights
    short* Wgb  = (short*)take(WB);
    short* Wob  = (short*)take(WB);
    short* MwT  = (short*)take(WB);
    float* bqkv = (float*)take(3072 * 4);
    float* bpw  = (float*)take(3072 * 4);
    short* xb   = (short*)take(XB);         // x bf16; reused as attn_out later
    short* pre  = (short*)take(3 * XB);     // QKV silu [8192][3072]; reused as qb/kb/vb
    short* post = (short*)take(3 * XB);     // conv out [8192][3072]; reused as scores+VT, gated

    short* qb = pre;
    short* kb = pre + BLD;
    short* vb = pre + 2 * BLD;
    short* scores = post;            // [4][2048][2048] bf16 = 2*BLD shorts
    short* VT = post + 2 * BLD;      // [4][1024][2048]
    short* aob = xb;                 // attn_out bf16 (xb dead after QKV GEMM)
    short* gated = post;             // gated bf16 (scores/VT dead after attn@V)
    (void)ws_size; (void)in_sizes; (void)n_in; (void)out_size;

    const long long sLD = (long long)LL * DD;   // 2048*1024
    const long long sLLb = (long long)LL * LL;  // 2048*2048

    k_zero1<<<1, 1, 0, stream>>>(loss);
    k_wcat<<<4096, 256, 0, stream>>>(wq, wk, wvw, pwq, pwk, pwv, wg, wo,
                                     Wqkv, Pqkv, Wgb, Wob);
    k_biascat<<<24, 256, 0, stream>>>(bq, bk, bvv, pwqb, pwkb, pwvb, bqkv, bpw);
    k_transpose_f32_bf16<<<dim3(16, 16, 1), 256, 0, stream>>>(memw, MwT, DD, DD);
    k_f32_to_bf16<<<4096, 256, 0, stream>>>(x, xb, (int)(BLD / 8));

    // fused QKV: silu(x @ [wq;wk;wv]^T + [bq;bk;bv]) -> pre [8192][3072]
    gemm<EPI_SILU><<<dim3(24, 64, 1), 256, 0, stream>>>(
        xb, 1024, 0, Wqkv, 1024, 0, pre, 3072, 0, bqkv, 0, nullptr, 1024, 0.f, nullptr);

    // fused depthwise conv: pre -> post (8 L-rows per thread, vector weights)
    k_dwconv3b<<<1536, 256, 0, stream>>>(pre, dwq, dwk, dwv, dwqb, dwkb, dwvb, post);

    // batched pointwise: z=3 branches; A = post columns z*1024.., out -> qb/kb/vb
    gemm<EPI_BIAS><<<dim3(8, 64, 3), 256, 0, stream>>>(
        post, 3072, 1024, Pqkv, 1024, (long long)DD * DD, qb, 1024, BLD,
        bpw, 1024, nullptr, 1024, 0.f, nullptr);

    // normalize qb AND kb in one launch (contiguous rows of pre) + V^T
    k_l2norm<<<16384, 256, 0, stream>>>(qb);
    k_transpose_bf16<<<dim3(16, 32, 4), 256, 0, stream>>>(vb, VT, 2048, 1024);

    // scores = Qn @ Kn^T / 32  (per batch)
    gemm<EPI_SCALE><<<dim3(16, 16, 4), 256, 0, stream>>>(
        qb, 1024, sLD, kb, 1024, sLD, scores, 2048, sLLb,
        nullptr, 0, nullptr, 1024, 0.03125f, nullptr);
    k_softmax<<<8192, 256, 0, stream>>>(scores);

    // attn_out = attn @ V  (W = V^T[d, l])
    gemm<EPI_PLAIN><<<dim3(8, 16, 4), 256, 0, stream>>>(
        scores, 2048, sLLb, VT, 2048, sLD, aob, 1024, sLD,
        nullptr, 0, nullptr, 2048, 0.f, nullptr);

    // gated = sigmoid(attn_out @ wg^T + bg) * attn_out
    gemm<EPI_GATE><<<dim3(8, 64, 1), 256, 0, stream>>>(
        aob, 1024, 0, Wgb, 1024, 0, gated, 1024, 0, bg, 0, aob, 1024, 0.f, nullptr);

    // out = gated @ wo^T + bo + x ; then LN in-place
    gemm<EPI_RESID><<<dim3(8, 64, 1), 256, 0, stream>>>(
        gated, 1024, 0, Wob, 1024, 0, out, 1024, 0, bo, 0, x, 1024, 0.f, nullptr);
    k_layernorm<<<8192, 256, 0, stream>>>(out, lng, lnb);

    // mem_loss = mean((Kn @ mem_w - V)^2)
    gemm<EPI_MLOSS><<<dim3(8, 64, 1), 256, 0, stream>>>(
        kb, 1024, 0, MwT, 1024, 0, nullptr, 1024, 0, nullptr, 0, vb,
        1024, 1.f / (float)BLD, loss);
}